// Round 2
// baseline (1343.818 us; speedup 1.0000x reference)
//
#include <hip/hip_runtime.h>

#define DEV __device__ __forceinline__

typedef __bf16 bf16x8 __attribute__((ext_vector_type(8)));
typedef float f32x4 __attribute__((ext_vector_type(4)));

static constexpr int SL = 48;     // src len == trg len
static constexpr int HH = 1024;   // hidden
static constexpr int G3 = 3072;   // 3*H

// ---------------- scalar helpers ----------------
DEV float bf2f(unsigned short u){ unsigned int x = ((unsigned int)u) << 16; float f; __builtin_memcpy(&f,&x,4); return f; }
DEV unsigned short f2bf(float f){ unsigned int x; __builtin_memcpy(&x,&f,4); x = (x + 0x7fffu + ((x>>16)&1u)) >> 16; return (unsigned short)x; }
DEV float sigmf(float x){ return 1.0f/(1.0f + expf(-x)); }

DEV void gload16(const void* g, void* l){
  __builtin_amdgcn_global_load_lds((__attribute__((address_space(1))) void*)g,
                                   (__attribute__((address_space(3))) void*)l, 16, 0, 0);
}

// ================= fp32 -> bf16 converters =================
__global__ void cvt_f32_bf16(const float* __restrict__ s, unsigned short* __restrict__ d, long n4){
  long i = blockIdx.x*(long)blockDim.x + threadIdx.x;
  const long stride = gridDim.x*(long)blockDim.x;
  for (; i < n4; i += stride){
    const float4 v = ((const float4*)s)[i];
    ushort4 o; o.x=f2bf(v.x); o.y=f2bf(v.y); o.z=f2bf(v.z); o.w=f2bf(v.w);
    ((ushort4*)d)[i] = o;
  }
}

__global__ void gather_cvt(const float* __restrict__ emb, const int* __restrict__ idx,
                           unsigned short* __restrict__ dst, int E){
  const int r = blockIdx.x;
  const int c = threadIdx.x * 4;
  const long row = idx[r];
  const float4 v = *(const float4*)(emb + row*(long)E + c);
  ushort4 o; o.x=f2bf(v.x); o.y=f2bf(v.y); o.z=f2bf(v.z); o.w=f2bf(v.w);
  *(ushort4*)(dst + (long)r*E + c) = o;
}

// ================= tiled GEMM: C[M,N] = A[M,K](bf16) @ Bw[N,K](bf16)^T + bias(f32) =================
// 128x128 tile, BK=64, 4 waves, global_load_lds width 16 (m97 structure).
template<int OUTBF16>
__global__ __launch_bounds__(256, 2)
void gemm_bt(const unsigned short* __restrict__ A,
             const unsigned short* __restrict__ Bw,
             const float* __restrict__ bias,
             void* __restrict__ Cout,
             int N, int K)
{
  __shared__ unsigned short Alds[128*64];
  __shared__ unsigned short Blds[128*64];
  const int tid  = threadIdx.x;
  const int lane = tid & 63;
  const int wave = tid >> 6;
  const int tn = blockIdx.x, tm = blockIdx.y;
  const int wm = (wave >> 1) * 64, wn = (wave & 1) * 64;

  f32x4 acc[4][4] = {};

  const int srow = tid >> 3;          // 0..31 (+32*rd)
  const int scol = (tid & 7) * 8;     // element offset in BK

  for (int ks = 0; ks < K; ks += 64) {
    #pragma unroll
    for (int rd = 0; rd < 4; ++rd) {
      const int r = rd*32 + srow;
      gload16(A  + (long)(tm*128 + r)*(long)K + ks + scol, &Alds[r*64 + scol]);
      gload16(Bw + (long)(tn*128 + r)*(long)K + ks + scol, &Blds[r*64 + scol]);
    }
    __syncthreads();
    #pragma unroll
    for (int kk = 0; kk < 2; ++kk) {
      bf16x8 af[4], bq[4];
      #pragma unroll
      for (int i=0;i<4;i++)
        af[i] = *(const bf16x8*)&Alds[(wm + i*16 + (lane&15))*64 + kk*32 + (lane>>4)*8];
      #pragma unroll
      for (int j=0;j<4;j++)
        bq[j] = *(const bf16x8*)&Blds[(wn + j*16 + (lane&15))*64 + kk*32 + (lane>>4)*8];
      #pragma unroll
      for (int i=0;i<4;i++)
        #pragma unroll
        for (int j=0;j<4;j++)
          acc[i][j] = __builtin_amdgcn_mfma_f32_16x16x32_bf16(af[i], bq[j], acc[i][j], 0,0,0);
    }
    __syncthreads();
  }

  const int c0 = lane & 15;
  const int r0 = (lane >> 4) * 4;
  #pragma unroll
  for (int j=0;j<4;j++){
    const int gcol = tn*128 + wn + j*16 + c0;
    const float bv = bias[gcol];
    #pragma unroll
    for (int i=0;i<4;i++){
      const long rowb = (long)(tm*128 + wm + i*16 + r0);
      #pragma unroll
      for (int r=0;r<4;r++){
        const float v = acc[i][j][r] + bv;
        const long off = (rowb + r)*(long)N + gcol;
        if (OUTBF16) ((unsigned short*)Cout)[off] = f2bf(v);
        else         ((float*)Cout)[off] = v;
      }
    }
  }
}

// ================= persistent GRU scan kernel =================
// 64 WGs x 256 thr. WG j owns H-columns [j*16, j*16+16). W slice (48 rows x 1024 bf16) in LDS,
// XOR-swizzled vs the 2048B row stride (ds_read_b128 conflict fix).

DEV int wswz(int row, int kbyte){ return (row*2048 + kbyte) ^ ((row & 7) << 4); }

DEV void load_w(char* WldsB, const unsigned short* Wsrc, int wg, int tid){
  for (int ch = tid; ch < 6144; ch += 256) {           // 48 rows * 128 chunks of 16B
    const int row = ch >> 7;
    const int kb  = (ch & 127) << 4;
    const int g = row >> 4, wr = row & 15;
    const char* src = (const char*)Wsrc + ((long)(g*HH + wg*16 + wr))*2048 + kb;
    *(uint4*)(WldsB + wswz(row, kb)) = *(const uint4*)src;
  }
}

// hg partials: wave (mt = wave&1 -> batch half, kh = wave>>1 -> K half)
DEV void step_gemm(const char* WldsB, const unsigned short* ch,
                   float* hgp, int lane, int wave)
{
  const int mt = wave & 1, kh = wave >> 1;
  const unsigned short* ah = ch + (mt*16 + (lane&15))*HH + kh*512 + (lane>>4)*8;
  const int rr0 = lane & 15;
  const int kb0 = kh*1024 + (lane>>4)*16;
  f32x4 a0 = {0.f,0.f,0.f,0.f}; f32x4 a1 = a0, a2 = a0;
  #pragma unroll
  for (int kk=0; kk<16; ++kk) {
    const bf16x8 av = *(const bf16x8*)(ah + kk*32);
    const bf16x8 b0 = *(const bf16x8*)(WldsB + wswz(rr0,      kb0 + kk*64));
    const bf16x8 b1 = *(const bf16x8*)(WldsB + wswz(rr0 + 16, kb0 + kk*64));
    const bf16x8 b2 = *(const bf16x8*)(WldsB + wswz(rr0 + 32, kb0 + kk*64));
    a0 = __builtin_amdgcn_mfma_f32_16x16x32_bf16(av, b0, a0, 0,0,0);
    a1 = __builtin_amdgcn_mfma_f32_16x16x32_bf16(av, b1, a1, 0,0,0);
    a2 = __builtin_amdgcn_mfma_f32_16x16x32_bf16(av, b2, a2, 0,0,0);
  }
  const int bb = mt*16 + (lane>>4)*4;
  #pragma unroll
  for (int r=0;r<4;r++){
    hgp[((kh*3+0)*32 + bb + r)*16 + rr0] = a0[r];
    hgp[((kh*3+1)*32 + bb + r)*16 + rr0] = a1[r];
    hgp[((kh*3+2)*32 + bb + r)*16 + rr0] = a2[r];
  }
}

// pg partials with B-frags straight from global Wp (one-time)
DEV void pg_gemm(const unsigned short* Wp, const unsigned short* ch,
                 float* hgp, int wg, int lane, int wave)
{
  const int mt = wave & 1, kh = wave >> 1;
  const unsigned short* ah = ch + (mt*16 + (lane&15))*HH + kh*512 + (lane>>4)*8;
  const unsigned short* w0 = Wp + ((long)(0*HH + wg*16 + (lane&15)))*HH + kh*512 + (lane>>4)*8;
  const unsigned short* w1 = Wp + ((long)(1*HH + wg*16 + (lane&15)))*HH + kh*512 + (lane>>4)*8;
  const unsigned short* w2 = Wp + ((long)(2*HH + wg*16 + (lane&15)))*HH + kh*512 + (lane>>4)*8;
  f32x4 a0 = {0.f,0.f,0.f,0.f}; f32x4 a1 = a0, a2 = a0;
  #pragma unroll
  for (int kk=0; kk<16; ++kk) {
    const bf16x8 av = *(const bf16x8*)(ah + kk*32);
    const bf16x8 b0 = *(const bf16x8*)(w0 + kk*32);
    const bf16x8 b1 = *(const bf16x8*)(w1 + kk*32);
    const bf16x8 b2 = *(const bf16x8*)(w2 + kk*32);
    a0 = __builtin_amdgcn_mfma_f32_16x16x32_bf16(av, b0, a0, 0,0,0);
    a1 = __builtin_amdgcn_mfma_f32_16x16x32_bf16(av, b1, a1, 0,0,0);
    a2 = __builtin_amdgcn_mfma_f32_16x16x32_bf16(av, b2, a2, 0,0,0);
  }
  const int rr0 = lane & 15;
  const int bb = mt*16 + (lane>>4)*4;
  #pragma unroll
  for (int r=0;r<4;r++){
    hgp[((kh*3+0)*32 + bb + r)*16 + rr0] = a0[r];
    hgp[((kh*3+1)*32 + bb + r)*16 + rr0] = a1[r];
    hgp[((kh*3+2)*32 + bb + r)*16 + rr0] = a2[r];
  }
}

// all-poll grid barrier: arrival flag per WG, every WG polls all 64 flags. 64 WGs co-resident.
DEV void grid_barrier(unsigned* slots, unsigned& id, int wg, int tid)
{
  const unsigned my = ++id;
  __syncthreads();                                     // drains each wave's stores (vmcnt 0)
  if (tid == 0)
    __hip_atomic_store(&slots[wg*32], my, __ATOMIC_RELEASE, __HIP_MEMORY_SCOPE_AGENT);
  if (tid < 64) {
    int guard = 0;
    while (__hip_atomic_load(&slots[tid*32], __ATOMIC_RELAXED, __HIP_MEMORY_SCOPE_AGENT) < my) {
      __builtin_amdgcn_s_sleep(1);
      if (++guard > 4000000) break;                    // fail loud instead of hanging
    }
    __threadfence();                                   // acquire: invalidate stale L1/L2 lines
  }
  __syncthreads();                                     // fence-then-barrier orders all waves' loads
}

__global__ __launch_bounds__(256, 1)
void scan_kernel(const unsigned short* __restrict__ Whh, const float* __restrict__ bhh,
                 const unsigned short* __restrict__ Wh,  const float* __restrict__ bh,
                 const unsigned short* __restrict__ Wp,  const float* __restrict__ bp,
                 const unsigned short* __restrict__ xg, const unsigned short* __restrict__ ig,
                 unsigned short* h0, unsigned short* h1,
                 unsigned short* trg_h,
                 unsigned* slots)
{
  extern __shared__ char smem[];
  char*  WldsB = smem;                                 // 98304 B (swizzled W slice)
  float* hgp   = (float*)(smem + 98304);               // [2][3][32][16] partials, 12288 B
  float* pgl   = (float*)(smem + 110592);              // [3][32][16], 6144 B
  float* biasl = (float*)(smem + 116736);              // [48] f32

  const int tid = threadIdx.x, wg = blockIdx.x;
  const int lane = tid & 63, wave = tid >> 6;
  unsigned barid = 0;
  float hreg[2] = {0.f, 0.f};                          // fp32 h for e=tid, e=tid+256

  load_w(WldsB, Whh, wg, tid);
  if (tid < 48) biasl[tid] = bhh[(tid>>4)*HH + wg*16 + (tid&15)];
  __syncthreads();

  // ---------------- encoder ----------------
  #pragma unroll 1
  for (int s = 0; s < SL; ++s) {
    const unsigned short* ch = (s & 1) ? h1 : h0;
    unsigned short* nh = (s & 1) ? h0 : h1;
    step_gemm(WldsB, ch, hgp, lane, wave);
    __syncthreads();
    #pragma unroll
    for (int u = 0; u < 2; ++u) {
      const int e = tid + u*256;
      const int b = e >> 4, c = e & 15;
      const unsigned short* xrow = xg + (long)(b*SL + s)*G3 + wg*16 + c;
      const float hr = hgp[e]        + hgp[1536 + e] + biasl[c];
      const float hz = hgp[512 + e]  + hgp[2048 + e] + biasl[16 + c];
      const float hn = hgp[1024 + e] + hgp[2560 + e] + biasl[32 + c];
      const float rg = sigmf(bf2f(xrow[0]) + hr);
      const float zg = sigmf(bf2f(xrow[1024]) + hz);
      const float ng = tanhf(bf2f(xrow[2048]) + rg*hn);
      const float hN = (1.f - zg)*ng + zg*hreg[u];
      hreg[u] = hN;
      nh[b*HH + wg*16 + c] = f2bf(hN);
    }
    grid_barrier(slots, barid, wg, tid);
  }

  // ---------------- pg = ctx @ Wp^T + bp (ctx = parity-0 h = final encoder h) ----------------
  pg_gemm(Wp, h0, hgp, wg, lane, wave);
  __syncthreads();
  #pragma unroll
  for (int u = 0; u < 2; ++u) {
    const int e = tid + u*256;
    const int c = e & 15;
    #pragma unroll
    for (int g = 0; g < 3; ++g)
      pgl[g*512 + e] = hgp[g*512 + e] + hgp[(3+g)*512 + e] + bp[g*HH + wg*16 + c];
  }
  __syncthreads();
  load_w(WldsB, Wh, wg, tid);
  if (tid < 48) biasl[tid] = bh[(tid>>4)*HH + wg*16 + (tid&15)];
  __syncthreads();

  // ---------------- decoder ----------------
  #pragma unroll 1
  for (int t = 0; t < SL; ++t) {
    const unsigned short* ch = (t & 1) ? h1 : h0;
    unsigned short* nh = (t & 1) ? h0 : h1;
    step_gemm(WldsB, ch, hgp, lane, wave);
    __syncthreads();
    #pragma unroll
    for (int u = 0; u < 2; ++u) {
      const int e = tid + u*256;
      const int b = e >> 4, c = e & 15;
      const unsigned short* irow = ig + (long)(b*SL + t)*G3 + wg*16 + c;
      const float hr = hgp[e]        + hgp[1536 + e] + biasl[c]      + pgl[e];
      const float hz = hgp[512 + e]  + hgp[2048 + e] + biasl[16 + c] + pgl[512 + e];
      const float hn = hgp[1024 + e] + hgp[2560 + e] + biasl[32 + c];
      const float rg = sigmf(bf2f(irow[0]) + hr);
      const float zg = sigmf(bf2f(irow[1024]) + hz);
      const float ng = tanhf(bf2f(irow[2048]) + rg*hn + pgl[1024 + e]);
      const float hN = ng + zg*(hreg[u] - ng);          // n + z*(h-n)
      hreg[u] = hN;
      const unsigned short hv = f2bf(hN);
      trg_h[(long)(b*SL + t)*HH + wg*16 + c] = hv;
      nh[b*HH + wg*16 + c] = hv;
    }
    if (t != SL-1) grid_barrier(slots, barid, wg, tid);
  }
}

// ================= host =================
extern "C" void kernel_launch(void* const* d_in, const int* in_sizes, int n_in,
                              void* d_out, int out_size, void* d_ws, size_t ws_size,
                              hipStream_t stream)
{
  (void)in_sizes; (void)n_in; (void)out_size; (void)ws_size;
  const int*   input_src = (const int*)d_in[0];
  const int*   input_trg = (const int*)d_in[1];
  const float* src_emb = (const float*)d_in[2];
  const float* trg_emb = (const float*)d_in[3];
  const float* enc_Wih = (const float*)d_in[4];
  const float* enc_Whh = (const float*)d_in[5];
  const float* enc_bih = (const float*)d_in[6];
  const float* enc_bhh = (const float*)d_in[7];
  const float* dec_Wi  = (const float*)d_in[8];
  const float* dec_bi  = (const float*)d_in[9];
  const float* dec_Wh  = (const float*)d_in[10];
  const float* dec_bh  = (const float*)d_in[11];
  const float* dec_Wp  = (const float*)d_in[12];
  const float* dec_bp  = (const float*)d_in[13];
  const float* out_W   = (const float*)d_in[14];
  const float* out_b   = (const float*)d_in[15];

  char* ws = (char*)d_ws;
  unsigned short* b16 = (unsigned short*)d_ws;
  unsigned* slots = (unsigned*)ws;                               // [0, 8192)
  unsigned short* h0     = (unsigned short*)(ws + 8192);         // 64 KB
  unsigned short* h1     = (unsigned short*)(ws + 73728);        // 64 KB
  unsigned short* trg_h  = (unsigned short*)(ws + 139264);       // 3.1 MB
  unsigned short* A_src  = (unsigned short*)(ws + 3284992);      // [1536][512]
  unsigned short* A_trg  = (unsigned short*)(ws + 4857856);
  unsigned short* Wih_b  = (unsigned short*)(ws + 6430720);      // [3072][512]
  unsigned short* Wi_b   = (unsigned short*)(ws + 9576448);
  unsigned short* Whh_b  = (unsigned short*)(ws + 12722176);     // [3072][1024]
  unsigned short* Wh_b   = (unsigned short*)(ws + 19013632);
  unsigned short* Wp_b   = (unsigned short*)(ws + 25305088);
  unsigned short* outW_b = (unsigned short*)(ws + 31596544);     // [32000][1024]
  unsigned short* xg     = (unsigned short*)(ws + 97132544);     // [1536][3072]
  unsigned short* ig     = (unsigned short*)(ws + 106569728);    // ends 116,006,912
  (void)b16;

  hipMemsetAsync(d_ws, 0, 73728, stream);                        // slots + h0

  // fp32 -> bf16 pre-converts
  gather_cvt<<<1536, 128, 0, stream>>>(src_emb, input_src, A_src, 512);
  gather_cvt<<<1536, 128, 0, stream>>>(trg_emb, input_trg, A_trg, 512);
  auto cvt = [&](const float* s, unsigned short* d, long n){
    long n4 = n >> 2;
    int grid = (int)((n4 + 255) >> 8); if (grid > 2048) grid = 2048;
    cvt_f32_bf16<<<grid, 256, 0, stream>>>(s, d, n4);
  };
  cvt(enc_Wih, Wih_b, 3072L*512);
  cvt(dec_Wi,  Wi_b,  3072L*512);
  cvt(enc_Whh, Whh_b, 3072L*1024);
  cvt(dec_Wh,  Wh_b,  3072L*1024);
  cvt(dec_Wp,  Wp_b,  3072L*1024);
  cvt(out_W,   outW_b, 32000L*1024);

  // xg = A_src @ Wih^T + bih ; ig = A_trg @ Wi^T + bi   (bf16 out)
  gemm_bt<1><<<dim3(24,12), 256, 0, stream>>>(A_src, Wih_b, enc_bih, xg, 3072, 512);
  gemm_bt<1><<<dim3(24,12), 256, 0, stream>>>(A_trg, Wi_b,  dec_bi,  ig, 3072, 512);

  constexpr int kSmem = 116928;
  (void)hipFuncSetAttribute(reinterpret_cast<const void*>(scan_kernel),
                            hipFuncAttributeMaxDynamicSharedMemorySize, kSmem);
  scan_kernel<<<64, 256, kSmem, stream>>>(Whh_b, enc_bhh, Wh_b, dec_bh, Wp_b, dec_bp,
                                          xg, ig, h0, h1, trg_h, slots);

  // logits = trg_h @ out_W^T + out_b  -> fp32 [1536][32000]
  gemm_bt<0><<<dim3(250,12), 256, 0, stream>>>(trg_h, outW_b, out_b, d_out, 32000, 1024);
}

// Round 3
// 1123.124 us; speedup vs baseline: 1.1965x; 1.1965x over previous
//
#include <hip/hip_runtime.h>

#define DEV __device__ __forceinline__

typedef __bf16 bf16x8 __attribute__((ext_vector_type(8)));
typedef float f32x4 __attribute__((ext_vector_type(4)));
typedef unsigned int u32x4 __attribute__((ext_vector_type(4)));

static constexpr int SL = 48;     // src len == trg len
static constexpr int HH = 1024;   // hidden
static constexpr int G3 = 3072;   // 3*H

// ---------------- scalar helpers ----------------
DEV float bf2f(unsigned short u){ unsigned int x = ((unsigned int)u) << 16; float f; __builtin_memcpy(&f,&x,4); return f; }
DEV unsigned short f2bf(float f){ unsigned int x; __builtin_memcpy(&x,&f,4); x = (x + 0x7fffu + ((x>>16)&1u)) >> 16; return (unsigned short)x; }
DEV float sigmf(float x){ return 1.0f/(1.0f + expf(-x)); }

DEV void gload16(const void* g, void* l){
  __builtin_amdgcn_global_load_lds((__attribute__((address_space(1))) void*)g,
                                   (__attribute__((address_space(3))) void*)l, 16, 0, 0);
}

// coherent (LLC-level) 16B load: bypasses possibly-stale per-XCD L2.
// NOTE: no waitcnt inside — caller must s_waitcnt vmcnt(0) before using results.
DEV u32x4 ld16_sc1(const void* p){
  u32x4 r;
  asm volatile("global_load_dwordx4 %0, %1, off sc0 sc1" : "=&v"(r) : "v"(p));
  return r;
}
// coherent 4B write-through store (visible at LLC once vmcnt acks)
DEV void st4_sc1(void* p, unsigned v){
  asm volatile("global_store_dword %0, %1, off sc0 sc1" :: "v"(p), "v"(v) : "memory");
}

// ================= fp32 -> bf16 converters =================
__global__ void cvt_f32_bf16(const float* __restrict__ s, unsigned short* __restrict__ d, long n4){
  long i = blockIdx.x*(long)blockDim.x + threadIdx.x;
  const long stride = gridDim.x*(long)blockDim.x;
  for (; i < n4; i += stride){
    const float4 v = ((const float4*)s)[i];
    ushort4 o; o.x=f2bf(v.x); o.y=f2bf(v.y); o.z=f2bf(v.z); o.w=f2bf(v.w);
    ((ushort4*)d)[i] = o;
  }
}

__global__ void gather_cvt(const float* __restrict__ emb, const int* __restrict__ idx,
                           unsigned short* __restrict__ dst, int E){
  const int r = blockIdx.x;
  const int c = threadIdx.x * 4;
  const long row = idx[r];
  const float4 v = *(const float4*)(emb + row*(long)E + c);
  ushort4 o; o.x=f2bf(v.x); o.y=f2bf(v.y); o.z=f2bf(v.z); o.w=f2bf(v.w);
  *(ushort4*)(dst + (long)r*E + c) = o;
}

// ================= tiled GEMM: C[M,N] = A[M,K](bf16) @ Bw[N,K](bf16)^T + bias(f32) =================
template<int OUTBF16>
__global__ __launch_bounds__(256, 2)
void gemm_bt(const unsigned short* __restrict__ A,
             const unsigned short* __restrict__ Bw,
             const float* __restrict__ bias,
             void* __restrict__ Cout,
             int N, int K)
{
  __shared__ unsigned short Alds[128*64];
  __shared__ unsigned short Blds[128*64];
  const int tid  = threadIdx.x;
  const int lane = tid & 63;
  const int wave = tid >> 6;
  const int tn = blockIdx.x, tm = blockIdx.y;
  const int wm = (wave >> 1) * 64, wn = (wave & 1) * 64;

  f32x4 acc[4][4] = {};

  const int srow = tid >> 3;          // 0..31 (+32*rd)
  const int scol = (tid & 7) * 8;     // element offset in BK

  for (int ks = 0; ks < K; ks += 64) {
    #pragma unroll
    for (int rd = 0; rd < 4; ++rd) {
      const int r = rd*32 + srow;
      gload16(A  + (long)(tm*128 + r)*(long)K + ks + scol, &Alds[r*64 + scol]);
      gload16(Bw + (long)(tn*128 + r)*(long)K + ks + scol, &Blds[r*64 + scol]);
    }
    __syncthreads();
    #pragma unroll
    for (int kk = 0; kk < 2; ++kk) {
      bf16x8 af[4], bq[4];
      #pragma unroll
      for (int i=0;i<4;i++)
        af[i] = *(const bf16x8*)&Alds[(wm + i*16 + (lane&15))*64 + kk*32 + (lane>>4)*8];
      #pragma unroll
      for (int j=0;j<4;j++)
        bq[j] = *(const bf16x8*)&Blds[(wn + j*16 + (lane&15))*64 + kk*32 + (lane>>4)*8];
      #pragma unroll
      for (int i=0;i<4;i++)
        #pragma unroll
        for (int j=0;j<4;j++)
          acc[i][j] = __builtin_amdgcn_mfma_f32_16x16x32_bf16(af[i], bq[j], acc[i][j], 0,0,0);
    }
    __syncthreads();
  }

  const int c0 = lane & 15;
  const int r0 = (lane >> 4) * 4;
  #pragma unroll
  for (int j=0;j<4;j++){
    const int gcol = tn*128 + wn + j*16 + c0;
    const float bv = bias[gcol];
    #pragma unroll
    for (int i=0;i<4;i++){
      const long rowb = (long)(tm*128 + wm + i*16 + r0);
      #pragma unroll
      for (int r=0;r<4;r++){
        const float v = acc[i][j][r] + bv;
        const long off = (rowb + r)*(long)N + gcol;
        if (OUTBF16) ((unsigned short*)Cout)[off] = f2bf(v);
        else         ((float*)Cout)[off] = v;
      }
    }
  }
}

// ================= persistent GRU scan kernel =================
// 64 WGs x 256 thr. WG j owns H-columns [j*16, j*16+16). W slice (48 rows x 1024 bf16) in LDS,
// XOR-swizzled vs the 2048B row stride (ds_read_b128 conflict fix).
// Cross-WG h exchange rides sc0/sc1 write-through stores + LLC loads: NO wbl2/buffer_inv.

DEV int wswz(int row, int kbyte){ return (row*2048 + kbyte) ^ ((row & 7) << 4); }

DEV void load_w(char* WldsB, const unsigned short* Wsrc, int wg, int tid){
  for (int ch = tid; ch < 6144; ch += 256) {           // 48 rows * 128 chunks of 16B
    const int row = ch >> 7;
    const int kb  = (ch & 127) << 4;
    const int g = row >> 4, wr = row & 15;
    const char* src = (const char*)Wsrc + ((long)(g*HH + wg*16 + wr))*2048 + kb;
    *(uint4*)(WldsB + wswz(row, kb)) = *(const uint4*)src;
  }
}

// hg partials: wave (mt = wave&1 -> batch half, kh = wave>>1 -> K half)
DEV void step_gemm(const char* WldsB, const unsigned short* ch,
                   float* hgp, int lane, int wave)
{
  const int mt = wave & 1, kh = wave >> 1;
  const unsigned short* ah = ch + (mt*16 + (lane&15))*HH + kh*512 + (lane>>4)*8;
  u32x4 hv[16];
  #pragma unroll
  for (int kk=0; kk<16; ++kk) hv[kk] = ld16_sc1(ah + kk*32);
  asm volatile("s_waitcnt vmcnt(0)" ::: "memory");
  __builtin_amdgcn_sched_barrier(0);

  const int rr0 = lane & 15;
  const int kb0 = kh*1024 + (lane>>4)*16;
  f32x4 a0 = {0.f,0.f,0.f,0.f}; f32x4 a1 = a0, a2 = a0;
  #pragma unroll
  for (int kk=0; kk<16; ++kk) {
    bf16x8 av; __builtin_memcpy(&av, &hv[kk], 16);
    const bf16x8 b0 = *(const bf16x8*)(WldsB + wswz(rr0,      kb0 + kk*64));
    const bf16x8 b1 = *(const bf16x8*)(WldsB + wswz(rr0 + 16, kb0 + kk*64));
    const bf16x8 b2 = *(const bf16x8*)(WldsB + wswz(rr0 + 32, kb0 + kk*64));
    a0 = __builtin_amdgcn_mfma_f32_16x16x32_bf16(av, b0, a0, 0,0,0);
    a1 = __builtin_amdgcn_mfma_f32_16x16x32_bf16(av, b1, a1, 0,0,0);
    a2 = __builtin_amdgcn_mfma_f32_16x16x32_bf16(av, b2, a2, 0,0,0);
  }
  const int bb = mt*16 + (lane>>4)*4;
  #pragma unroll
  for (int r=0;r<4;r++){
    hgp[((kh*3+0)*32 + bb + r)*16 + rr0] = a0[r];
    hgp[((kh*3+1)*32 + bb + r)*16 + rr0] = a1[r];
    hgp[((kh*3+2)*32 + bb + r)*16 + rr0] = a2[r];
  }
}

// pg partials with B-frags straight from global Wp (one-time)
DEV void pg_gemm(const unsigned short* Wp, const unsigned short* ch,
                 float* hgp, int wg, int lane, int wave)
{
  const int mt = wave & 1, kh = wave >> 1;
  const unsigned short* ah = ch + (mt*16 + (lane&15))*HH + kh*512 + (lane>>4)*8;
  const unsigned short* w0 = Wp + ((long)(0*HH + wg*16 + (lane&15)))*HH + kh*512 + (lane>>4)*8;
  const unsigned short* w1 = Wp + ((long)(1*HH + wg*16 + (lane&15)))*HH + kh*512 + (lane>>4)*8;
  const unsigned short* w2 = Wp + ((long)(2*HH + wg*16 + (lane&15)))*HH + kh*512 + (lane>>4)*8;
  u32x4 hv[16];
  #pragma unroll
  for (int kk=0; kk<16; ++kk) hv[kk] = ld16_sc1(ah + kk*32);
  asm volatile("s_waitcnt vmcnt(0)" ::: "memory");
  __builtin_amdgcn_sched_barrier(0);
  f32x4 a0 = {0.f,0.f,0.f,0.f}; f32x4 a1 = a0, a2 = a0;
  #pragma unroll
  for (int kk=0; kk<16; ++kk) {
    bf16x8 av; __builtin_memcpy(&av, &hv[kk], 16);
    const bf16x8 b0 = *(const bf16x8*)(w0 + kk*32);
    const bf16x8 b1 = *(const bf16x8*)(w1 + kk*32);
    const bf16x8 b2 = *(const bf16x8*)(w2 + kk*32);
    a0 = __builtin_amdgcn_mfma_f32_16x16x32_bf16(av, b0, a0, 0,0,0);
    a1 = __builtin_amdgcn_mfma_f32_16x16x32_bf16(av, b1, a1, 0,0,0);
    a2 = __builtin_amdgcn_mfma_f32_16x16x32_bf16(av, b2, a2, 0,0,0);
  }
  const int rr0 = lane & 15;
  const int bb = mt*16 + (lane>>4)*4;
  #pragma unroll
  for (int r=0;r<4;r++){
    hgp[((kh*3+0)*32 + bb + r)*16 + rr0] = a0[r];
    hgp[((kh*3+1)*32 + bb + r)*16 + rr0] = a1[r];
    hgp[((kh*3+2)*32 + bb + r)*16 + rr0] = a2[r];
  }
}

// all-poll grid barrier, RELAXED flags only (data already at LLC via sc1 write-through).
DEV void grid_barrier(unsigned* slots, unsigned& id, int wg, int tid)
{
  const unsigned my = ++id;
  asm volatile("s_waitcnt vmcnt(0)" ::: "memory");     // sc1 h-stores acked at LLC
  __syncthreads();                                     // all waves of this WG done
  if (tid == 0)
    __hip_atomic_store(&slots[wg*32], my, __ATOMIC_RELAXED, __HIP_MEMORY_SCOPE_AGENT);
  if (tid < 64) {
    int guard = 0;
    while (__hip_atomic_load(&slots[tid*32], __ATOMIC_RELAXED, __HIP_MEMORY_SCOPE_AGENT) < my) {
      __builtin_amdgcn_s_sleep(1);
      if (++guard > 4000000) break;                    // fail loud instead of hanging
    }
  }
  __syncthreads();                                     // whole WG held until flags seen
}

__global__ __launch_bounds__(256, 1)
void scan_kernel(const unsigned short* __restrict__ Whh, const float* __restrict__ bhh,
                 const unsigned short* __restrict__ Wh,  const float* __restrict__ bh,
                 const unsigned short* __restrict__ Wp,  const float* __restrict__ bp,
                 const unsigned short* __restrict__ xg, const unsigned short* __restrict__ ig,
                 unsigned short* h0, unsigned short* h1,
                 unsigned short* trg_h,
                 unsigned* slots)
{
  extern __shared__ char smem[];
  char*  WldsB = smem;                                 // 98304 B (swizzled W slice)
  float* hgp   = (float*)(smem + 98304);               // [2][3][32][16] partials, 12288 B
  float* pgl   = (float*)(smem + 110592);              // [3][32][16], 6144 B
  float* biasl = (float*)(smem + 116736);              // [48] f32

  const int tid = threadIdx.x, wg = blockIdx.x;
  const int lane = tid & 63, wave = tid >> 6;
  unsigned barid = 0;

  // pair mapping: thread handles elements e0=2*tid, e0+1  (b = batch row, c0 = col pair)
  const int pb = tid >> 3;            // 0..31
  const int pc = (tid & 7) * 2;       // 0,2,..,14
  const int e0 = pb*16 + pc;          // = 2*tid
  float hreg[2] = {0.f, 0.f};         // fp32 h for e0, e0+1

  load_w(WldsB, Whh, wg, tid);
  if (tid < 48) biasl[tid] = bhh[(tid>>4)*HH + wg*16 + (tid&15)];
  __syncthreads();

  // ---------------- encoder ----------------
  #pragma unroll 1
  for (int s = 0; s < SL; ++s) {
    const unsigned short* ch = (s & 1) ? h1 : h0;
    unsigned short* nh = (s & 1) ? h0 : h1;
    step_gemm(WldsB, ch, hgp, lane, wave);
    __syncthreads();
    {
      const unsigned short* xrow = xg + (long)(pb*SL + s)*G3 + wg*16 + pc;
      const unsigned xr = *(const unsigned*)(xrow);
      const unsigned xz = *(const unsigned*)(xrow + 1024);
      const unsigned xn = *(const unsigned*)(xrow + 2048);
      unsigned packed = 0;
      #pragma unroll
      for (int j = 0; j < 2; ++j) {
        const int e = e0 + j, c = pc + j;
        const float hr = hgp[e]        + hgp[1536 + e] + biasl[c];
        const float hz = hgp[512 + e]  + hgp[2048 + e] + biasl[16 + c];
        const float hn = hgp[1024 + e] + hgp[2560 + e] + biasl[32 + c];
        const float rg = sigmf(bf2f((unsigned short)(xr >> (16*j))) + hr);
        const float zg = sigmf(bf2f((unsigned short)(xz >> (16*j))) + hz);
        const float ng = tanhf(bf2f((unsigned short)(xn >> (16*j))) + rg*hn);
        const float hN = (1.f - zg)*ng + zg*hreg[j];
        hreg[j] = hN;
        packed |= ((unsigned)f2bf(hN)) << (16*j);
      }
      st4_sc1(nh + pb*HH + wg*16 + pc, packed);
    }
    grid_barrier(slots, barid, wg, tid);
  }

  // ---------------- pg = ctx @ Wp^T + bp (ctx = final encoder h, in h0) ----------------
  pg_gemm(Wp, h0, hgp, wg, lane, wave);
  __syncthreads();
  #pragma unroll
  for (int j = 0; j < 2; ++j) {
    const int e = e0 + j, c = pc + j;
    #pragma unroll
    for (int g = 0; g < 3; ++g)
      pgl[g*512 + e] = hgp[g*512 + e] + hgp[(3+g)*512 + e] + bp[g*HH + wg*16 + c];
  }
  __syncthreads();
  load_w(WldsB, Wh, wg, tid);
  if (tid < 48) biasl[tid] = bh[(tid>>4)*HH + wg*16 + (tid&15)];
  __syncthreads();

  // ---------------- decoder ----------------
  #pragma unroll 1
  for (int t = 0; t < SL; ++t) {
    const unsigned short* ch = (t & 1) ? h1 : h0;
    unsigned short* nh = (t & 1) ? h0 : h1;
    step_gemm(WldsB, ch, hgp, lane, wave);
    __syncthreads();
    {
      const unsigned short* irow = ig + (long)(pb*SL + t)*G3 + wg*16 + pc;
      const unsigned xr = *(const unsigned*)(irow);
      const unsigned xz = *(const unsigned*)(irow + 1024);
      const unsigned xn = *(const unsigned*)(irow + 2048);
      unsigned packed = 0;
      #pragma unroll
      for (int j = 0; j < 2; ++j) {
        const int e = e0 + j, c = pc + j;
        const float hr = hgp[e]        + hgp[1536 + e] + biasl[c]      + pgl[e];
        const float hz = hgp[512 + e]  + hgp[2048 + e] + biasl[16 + c] + pgl[512 + e];
        const float hn = hgp[1024 + e] + hgp[2560 + e] + biasl[32 + c];
        const float rg = sigmf(bf2f((unsigned short)(xr >> (16*j))) + hr);
        const float zg = sigmf(bf2f((unsigned short)(xz >> (16*j))) + hz);
        const float ng = tanhf(bf2f((unsigned short)(xn >> (16*j))) + rg*hn + pgl[1024 + e]);
        const float hN = ng + zg*(hreg[j] - ng);        // n + z*(h-n)
        hreg[j] = hN;
        packed |= ((unsigned)f2bf(hN)) << (16*j);
      }
      *(unsigned*)(trg_h + (long)(pb*SL + t)*HH + wg*16 + pc) = packed;  // plain store (next dispatch reads)
      if (t != SL-1) st4_sc1(nh + pb*HH + wg*16 + pc, packed);
    }
    if (t != SL-1) grid_barrier(slots, barid, wg, tid);
  }
}

// ================= host =================
extern "C" void kernel_launch(void* const* d_in, const int* in_sizes, int n_in,
                              void* d_out, int out_size, void* d_ws, size_t ws_size,
                              hipStream_t stream)
{
  (void)in_sizes; (void)n_in; (void)out_size; (void)ws_size;
  const int*   input_src = (const int*)d_in[0];
  const int*   input_trg = (const int*)d_in[1];
  const float* src_emb = (const float*)d_in[2];
  const float* trg_emb = (const float*)d_in[3];
  const float* enc_Wih = (const float*)d_in[4];
  const float* enc_Whh = (const float*)d_in[5];
  const float* enc_bih = (const float*)d_in[6];
  const float* enc_bhh = (const float*)d_in[7];
  const float* dec_Wi  = (const float*)d_in[8];
  const float* dec_bi  = (const float*)d_in[9];
  const float* dec_Wh  = (const float*)d_in[10];
  const float* dec_bh  = (const float*)d_in[11];
  const float* dec_Wp  = (const float*)d_in[12];
  const float* dec_bp  = (const float*)d_in[13];
  const float* out_W   = (const float*)d_in[14];
  const float* out_b   = (const float*)d_in[15];

  char* ws = (char*)d_ws;
  unsigned* slots = (unsigned*)ws;                               // [0, 8192)
  unsigned short* h0     = (unsigned short*)(ws + 8192);         // 64 KB
  unsigned short* h1     = (unsigned short*)(ws + 73728);        // 64 KB
  unsigned short* trg_h  = (unsigned short*)(ws + 139264);       // 3.1 MB
  unsigned short* A_src  = (unsigned short*)(ws + 3284992);      // [1536][512]
  unsigned short* A_trg  = (unsigned short*)(ws + 4857856);
  unsigned short* Wih_b  = (unsigned short*)(ws + 6430720);      // [3072][512]
  unsigned short* Wi_b   = (unsigned short*)(ws + 9576448);
  unsigned short* Whh_b  = (unsigned short*)(ws + 12722176);     // [3072][1024]
  unsigned short* Wh_b   = (unsigned short*)(ws + 19013632);
  unsigned short* Wp_b   = (unsigned short*)(ws + 25305088);
  unsigned short* outW_b = (unsigned short*)(ws + 31596544);     // [32000][1024]
  unsigned short* xg     = (unsigned short*)(ws + 97132544);     // [1536][3072]
  unsigned short* ig     = (unsigned short*)(ws + 106569728);    // ends 116,006,912

  hipMemsetAsync(d_ws, 0, 73728, stream);                        // slots + h0

  // fp32 -> bf16 pre-converts
  gather_cvt<<<1536, 128, 0, stream>>>(src_emb, input_src, A_src, 512);
  gather_cvt<<<1536, 128, 0, stream>>>(trg_emb, input_trg, A_trg, 512);
  auto cvt = [&](const float* s, unsigned short* d, long n){
    long n4 = n >> 2;
    int grid = (int)((n4 + 255) >> 8); if (grid > 2048) grid = 2048;
    cvt_f32_bf16<<<grid, 256, 0, stream>>>(s, d, n4);
  };
  cvt(enc_Wih, Wih_b, 3072L*512);
  cvt(dec_Wi,  Wi_b,  3072L*512);
  cvt(enc_Whh, Whh_b, 3072L*1024);
  cvt(dec_Wh,  Wh_b,  3072L*1024);
  cvt(dec_Wp,  Wp_b,  3072L*1024);
  cvt(out_W,   outW_b, 32000L*1024);

  // xg = A_src @ Wih^T + bih ; ig = A_trg @ Wi^T + bi   (bf16 out)
  gemm_bt<1><<<dim3(24,12), 256, 0, stream>>>(A_src, Wih_b, enc_bih, xg, 3072, 512);
  gemm_bt<1><<<dim3(24,12), 256, 0, stream>>>(A_trg, Wi_b,  dec_bi,  ig, 3072, 512);

  constexpr int kSmem = 116928;
  (void)hipFuncSetAttribute(reinterpret_cast<const void*>(scan_kernel),
                            hipFuncAttributeMaxDynamicSharedMemorySize, kSmem);
  scan_kernel<<<64, 256, kSmem, stream>>>(Whh_b, enc_bhh, Wh_b, dec_bh, Wp_b, dec_bp,
                                          xg, ig, h0, h1, trg_h, slots);

  // logits = trg_h @ out_W^T + out_b  -> fp32 [1536][32000]
  gemm_bt<0><<<dim3(250,12), 256, 0, stream>>>(trg_h, outW_b, out_b, d_out, 32000, 1024);
}